// Round 1
// baseline (1464.070 us; speedup 1.0000x reference)
//
#include <hip/hip_runtime.h>

#define NN 50000
#define NE 800000
#define DD 128

// h = x @ W^T + b  ; also writes out = h (residual base for scatter-add).
// W staged in LDS padded to 132 floats/row: b128 reads of W[j][k..k+3] give
// group index (33j + k/4) % 8 -> 8 lanes/4-bank-group = LDS-BW minimum.
__global__ __launch_bounds__(256) void gemm_kernel(
    const float* __restrict__ x, const float* __restrict__ W,
    const float* __restrict__ b, float* __restrict__ h,
    float* __restrict__ out)
{
    __shared__ float Wl[128 * 132];
    __shared__ float xl[8 * 128];

    // Stage W (64 KB) once per block, coalesced float4 loads.
    for (int i = threadIdx.x; i < 128 * 32; i += 256) {
        int r  = i >> 5;
        int c4 = (i & 31) << 2;
        const float4 w4 = *(const float4*)(W + r * 128 + c4);
        float* dst = &Wl[r * 132 + c4];
        dst[0] = w4.x; dst[1] = w4.y; dst[2] = w4.z; dst[3] = w4.w;
    }

    const int j    = threadIdx.x & 127;   // output column
    const int half = threadIdx.x >> 7;    // 0..1 -> which 4-row slice
    const float bj = b[j];
    __syncthreads();

    // 50000 rows in 6250 groups of 8
    for (int g = blockIdx.x; g < NN / 8; g += gridDim.x) {
        // Stage 8 rows of x (4 KB): exactly one float4 per thread, coalesced.
        {
            const float4 v = *(const float4*)(x + (size_t)g * 8 * 128 + threadIdx.x * 4);
            *(float4*)(xl + threadIdx.x * 4) = v;
        }
        __syncthreads();

        float acc0 = bj, acc1 = bj, acc2 = bj, acc3 = bj;
        const float* xr = xl + half * 4 * 128;
#pragma unroll
        for (int k = 0; k < 128; k += 4) {
            const float4 w4 = *(const float4*)&Wl[j * 132 + k];
            const float4 x0 = *(const float4*)&xr[0 * 128 + k];  // wave-broadcast
            const float4 x1 = *(const float4*)&xr[1 * 128 + k];
            const float4 x2 = *(const float4*)&xr[2 * 128 + k];
            const float4 x3 = *(const float4*)&xr[3 * 128 + k];
            acc0 += w4.x * x0.x + w4.y * x0.y + w4.z * x0.z + w4.w * x0.w;
            acc1 += w4.x * x1.x + w4.y * x1.y + w4.z * x1.z + w4.w * x1.w;
            acc2 += w4.x * x2.x + w4.y * x2.y + w4.z * x2.z + w4.w * x2.w;
            acc3 += w4.x * x3.x + w4.y * x3.y + w4.z * x3.z + w4.w * x3.w;
        }

        const int rowbase = g * 8 + half * 4;
        {
            size_t o0 = (size_t)(rowbase + 0) * 128 + j;
            size_t o1 = (size_t)(rowbase + 1) * 128 + j;
            size_t o2 = (size_t)(rowbase + 2) * 128 + j;
            size_t o3 = (size_t)(rowbase + 3) * 128 + j;
            h[o0] = acc0; out[o0] = acc0;
            h[o1] = acc1; out[o1] = acc1;
            h[o2] = acc2; out[o2] = acc2;
            h[o3] = acc3; out[o3] = acc3;
        }
        __syncthreads();  // protect xl before next stage
    }
}

// One 32-thread group per edge: coalesced 512 B gather of h[col],
// 4 fp32 atomicAdds per thread into out[row].
__global__ __launch_bounds__(256) void scatter_kernel(
    const int* __restrict__ idx, const float* __restrict__ h,
    float* __restrict__ out)
{
    const int gid = blockIdx.x * 256 + threadIdx.x;
    const int e = gid >> 5;
    if (e >= NE) return;
    const int l = gid & 31;

    const int row = idx[e];        // destination (segment id)
    const int col = idx[NE + e];   // source node

    const float4 v = *(const float4*)(h + (size_t)col * 128 + l * 4);
    float* o = out + (size_t)row * 128 + l * 4;
    atomicAdd(o + 0, v.x);
    atomicAdd(o + 1, v.y);
    atomicAdd(o + 2, v.z);
    atomicAdd(o + 3, v.w);
}

extern "C" void kernel_launch(void* const* d_in, const int* in_sizes, int n_in,
                              void* d_out, int out_size, void* d_ws, size_t ws_size,
                              hipStream_t stream)
{
    const float* x  = (const float*)d_in[0];
    const int*   ei = (const int*)d_in[1];   // int32 (JAX canonicalizes int64)
    const float* W  = (const float*)d_in[2];
    const float* b  = (const float*)d_in[3];
    float* out = (float*)d_out;
    float* h   = (float*)d_ws;               // 25.6 MB scratch for projected features

    gemm_kernel<<<1024, 256, 0, stream>>>(x, W, b, h, out);

    const int total = NE * 32;               // 32 threads per edge
    scatter_kernel<<<total / 256, 256, 0, stream>>>(ei, h, out);
}

// Round 2
// 364.349 us; speedup vs baseline: 4.0183x; 4.0183x over previous
//
#include <hip/hip_runtime.h>

#define NN 50000
#define NE 800000
#define DD 128

// ---------------- GEMM: h = x @ W^T + b ----------------
// W staged in LDS padded to 132 floats/row (conflict-minimal b128 reads).
__global__ __launch_bounds__(256) void gemm_kernel(
    const float* __restrict__ x, const float* __restrict__ W,
    const float* __restrict__ b, float* __restrict__ h)
{
    __shared__ float Wl[128 * 132];
    __shared__ float xl[8 * 128];

    for (int i = threadIdx.x; i < 128 * 32; i += 256) {
        int r  = i >> 5;
        int c4 = (i & 31) << 2;
        const float4 w4 = *(const float4*)(W + r * 128 + c4);
        float* dst = &Wl[r * 132 + c4];
        dst[0] = w4.x; dst[1] = w4.y; dst[2] = w4.z; dst[3] = w4.w;
    }

    const int j    = threadIdx.x & 127;
    const int half = threadIdx.x >> 7;
    const float bj = b[j];
    __syncthreads();

    for (int g = blockIdx.x; g < NN / 8; g += gridDim.x) {
        {
            const float4 v = *(const float4*)(x + (size_t)g * 8 * 128 + threadIdx.x * 4);
            *(float4*)(xl + threadIdx.x * 4) = v;
        }
        __syncthreads();

        float acc0 = bj, acc1 = bj, acc2 = bj, acc3 = bj;
        const float* xr = xl + half * 4 * 128;
#pragma unroll
        for (int k = 0; k < 128; k += 4) {
            const float4 w4 = *(const float4*)&Wl[j * 132 + k];
            const float4 x0 = *(const float4*)&xr[0 * 128 + k];
            const float4 x1 = *(const float4*)&xr[1 * 128 + k];
            const float4 x2 = *(const float4*)&xr[2 * 128 + k];
            const float4 x3 = *(const float4*)&xr[3 * 128 + k];
            acc0 += w4.x * x0.x + w4.y * x0.y + w4.z * x0.z + w4.w * x0.w;
            acc1 += w4.x * x1.x + w4.y * x1.y + w4.z * x1.z + w4.w * x1.w;
            acc2 += w4.x * x2.x + w4.y * x2.y + w4.z * x2.z + w4.w * x2.w;
            acc3 += w4.x * x3.x + w4.y * x3.y + w4.z * x3.z + w4.w * x3.w;
        }

        const int rowbase = g * 8 + half * 4;
        h[(size_t)(rowbase + 0) * 128 + j] = acc0;
        h[(size_t)(rowbase + 1) * 128 + j] = acc1;
        h[(size_t)(rowbase + 2) * 128 + j] = acc2;
        h[(size_t)(rowbase + 3) * 128 + j] = acc3;
        __syncthreads();
    }
}

// ---------------- CSR construction ----------------
__global__ __launch_bounds__(256) void zero_deg_kernel(int* __restrict__ deg)
{
    int i = blockIdx.x * 256 + threadIdx.x;
    if (i < NN) deg[i] = 0;
}

__global__ __launch_bounds__(256) void hist_kernel(
    const int* __restrict__ ei, int* __restrict__ deg)
{
    int e = blockIdx.x * 256 + threadIdx.x;
    if (e < NE) atomicAdd(&deg[ei[e]], 1);
}

// Single-block exclusive scan of deg[NN] -> start[NN+1]; copies to cursor.
__global__ __launch_bounds__(1024) void scan_kernel(
    const int* __restrict__ deg, int* __restrict__ start, int* __restrict__ cursor)
{
    __shared__ int sdata[1024];
    const int tid = threadIdx.x;
    int running = 0;
    const int nchunks = (NN + 1023) / 1024;
    for (int c = 0; c < nchunks; ++c) {
        const int i = c * 1024 + tid;
        const int v = (i < NN) ? deg[i] : 0;
        sdata[tid] = v;
        __syncthreads();
        for (int off = 1; off < 1024; off <<= 1) {
            int t = 0;
            if (tid >= off) t = sdata[tid - off];
            __syncthreads();
            sdata[tid] += t;
            __syncthreads();
        }
        const int incl = sdata[tid];
        if (i < NN) {
            const int excl = running + incl - v;
            start[i]  = excl;
            cursor[i] = excl;
        }
        running += sdata[1023];
        __syncthreads();
    }
    if (tid == 0) start[NN] = running;  // == NE
}

__global__ __launch_bounds__(256) void scatter_pos_kernel(
    const int* __restrict__ ei, int* __restrict__ cursor,
    int* __restrict__ sorted_col)
{
    int e = blockIdx.x * 256 + threadIdx.x;
    if (e < NE) {
        const int r = ei[e];
        const int p = atomicAdd(&cursor[r], 1);
        sorted_col[p] = ei[NE + e];
    }
}

// ---------------- Aggregate: out[n] = h[n] + sum_{e: row=n} h[col_e] ----
// One 128-thread block (2 waves) per node; edge list staged in LDS.
__global__ __launch_bounds__(128) void agg_kernel(
    const int* __restrict__ start, const int* __restrict__ scol,
    const float* __restrict__ h, float* __restrict__ out)
{
    const int n = blockIdx.x;
    const int j = threadIdx.x;
    const int s = start[n];
    const int e = start[n + 1];

    float acc = h[(size_t)n * 128 + j];

    __shared__ int cols[128];
    for (int base = s; base < e; base += 128) {
        const int cnt = min(128, e - base);
        if (j < cnt) cols[j] = scol[base + j];
        __syncthreads();
        int k = 0;
        for (; k + 4 <= cnt; k += 4) {
            const float a0 = h[(size_t)cols[k + 0] * 128 + j];
            const float a1 = h[(size_t)cols[k + 1] * 128 + j];
            const float a2 = h[(size_t)cols[k + 2] * 128 + j];
            const float a3 = h[(size_t)cols[k + 3] * 128 + j];
            acc += a0; acc += a1; acc += a2; acc += a3;
        }
        for (; k < cnt; ++k) acc += h[(size_t)cols[k] * 128 + j];
        __syncthreads();
    }

    out[(size_t)n * 128 + j] = acc;
}

extern "C" void kernel_launch(void* const* d_in, const int* in_sizes, int n_in,
                              void* d_out, int out_size, void* d_ws, size_t ws_size,
                              hipStream_t stream)
{
    const float* x  = (const float*)d_in[0];
    const int*   ei = (const int*)d_in[1];   // int32
    const float* W  = (const float*)d_in[2];
    const float* b  = (const float*)d_in[3];
    float* out = (float*)d_out;

    // Workspace layout
    float* h          = (float*)d_ws;                      // NN*DD floats (25.6 MB)
    int*   deg        = (int*)(h + (size_t)NN * DD);       // NN
    int*   start      = deg + NN;                          // NN+1
    int*   cursor     = start + NN + 1;                    // NN
    int*   sorted_col = cursor + NN;                       // NE

    zero_deg_kernel<<<(NN + 255) / 256, 256, 0, stream>>>(deg);
    hist_kernel<<<(NE + 255) / 256, 256, 0, stream>>>(ei, deg);
    scan_kernel<<<1, 1024, 0, stream>>>(deg, start, cursor);
    scatter_pos_kernel<<<(NE + 255) / 256, 256, 0, stream>>>(ei, cursor, sorted_col);

    gemm_kernel<<<1024, 256, 0, stream>>>(x, W, b, h);

    agg_kernel<<<NN, 128, 0, stream>>>(start, sorted_col, h, out);
}

// Round 3
// 246.125 us; speedup vs baseline: 5.9485x; 1.4803x over previous
//
#include <hip/hip_runtime.h>

#define NN 50000
#define NE 800000
#define DD 128
#define TILE_M 64
#define WPAD 136          // 128 + 8 bf16 pad -> 2-way-max LDS bank aliasing (free)
#define NB_SCAN ((NN + 255) / 256)   // 196 scan blocks

typedef __attribute__((ext_vector_type(8))) short short8;
typedef __attribute__((ext_vector_type(4))) float f32x4;

__device__ __forceinline__ unsigned short f2bf(float f) {
    unsigned int u = __float_as_uint(f);
    u += 0x7fffu + ((u >> 16) & 1u);   // RNE
    return (unsigned short)(u >> 16);
}

// ---------------- GEMM: h = x @ W^T + b  (bf16 MFMA) ----------------
// 782 blocks, one 64-row tile each. W (bf16) + x-tile (bf16) staged in LDS.
__global__ __launch_bounds__(256) void gemm_mfma(
    const float* __restrict__ x, const float* __restrict__ W,
    const float* __restrict__ b, float* __restrict__ h)
{
    __shared__ unsigned short Wl[128 * WPAD];     // 34.8 KB
    __shared__ unsigned short xl[TILE_M * WPAD];  // 17.4 KB

    const int t = threadIdx.x;

    // Stage W: 128x128 fp32 -> bf16, float4-granular (16 iters/thread).
    for (int i = t; i < 128 * 32; i += 256) {
        const int r = i >> 5, c4 = (i & 31) << 2;
        const float4 w4 = *(const float4*)(W + r * 128 + c4);
        unsigned short* dst = &Wl[r * WPAD + c4];
        dst[0] = f2bf(w4.x); dst[1] = f2bf(w4.y);
        dst[2] = f2bf(w4.z); dst[3] = f2bf(w4.w);
    }

    // Stage x tile: 64 rows x 128 cols (8 float4/thread), row-clamped.
    const int row0 = blockIdx.x * TILE_M;
#pragma unroll
    for (int i = 0; i < 8; ++i) {
        const int idx = i * 256 + t;
        const int r = idx >> 5, c4 = (idx & 31) << 2;
        int gr = row0 + r; if (gr > NN - 1) gr = NN - 1;
        const float4 v = *(const float4*)(x + (size_t)gr * 128 + c4);
        unsigned short* dst = &xl[r * WPAD + c4];
        dst[0] = f2bf(v.x); dst[1] = f2bf(v.y);
        dst[2] = f2bf(v.z); dst[3] = f2bf(v.w);
    }

    const int lane = t & 63;
    const int wave = t >> 6;       // 0..3 -> 16-row strip
    const int m16  = lane & 15;
    const int quad = lane >> 4;

    float bias[8];
#pragma unroll
    for (int nt = 0; nt < 8; ++nt) bias[nt] = b[nt * 16 + m16];

    __syncthreads();

    // A frags: row = wave*16 + m16, k = kc*32 + quad*8 + j  (one b128 each)
    const int am = wave * 16 + m16;
    short8 afrag[4];
#pragma unroll
    for (int kc = 0; kc < 4; ++kc)
        afrag[kc] = *(const short8*)&xl[am * WPAD + kc * 32 + quad * 8];

    f32x4 acc[8];
#pragma unroll
    for (int nt = 0; nt < 8; ++nt) acc[nt] = (f32x4){0.f, 0.f, 0.f, 0.f};

#pragma unroll
    for (int kc = 0; kc < 4; ++kc) {
#pragma unroll
        for (int nt = 0; nt < 8; ++nt) {
            const short8 bfrag =
                *(const short8*)&Wl[(nt * 16 + m16) * WPAD + kc * 32 + quad * 8];
            acc[nt] = __builtin_amdgcn_mfma_f32_16x16x32_bf16(
                afrag[kc], bfrag, acc[nt], 0, 0, 0);
        }
    }

    // Epilogue: C/D -> lane holds col n = nt*16 + m16, rows quad*4 + r.
    const int rbase = row0 + wave * 16 + quad * 4;
#pragma unroll
    for (int nt = 0; nt < 8; ++nt) {
#pragma unroll
        for (int r = 0; r < 4; ++r) {
            const int grow = rbase + r;
            if (grow < NN)
                h[(size_t)grow * 128 + nt * 16 + m16] = acc[nt][r] + bias[nt];
        }
    }
}

// ---------------- CSR construction ----------------
__global__ __launch_bounds__(256) void zero_deg_kernel(int* __restrict__ deg)
{
    const int i = blockIdx.x * 256 + threadIdx.x;
    if (i < NN) deg[i] = 0;
}

__global__ __launch_bounds__(256) void hist_kernel(
    const int* __restrict__ ei, int* __restrict__ deg)
{
    const int e = blockIdx.x * 256 + threadIdx.x;
    if (e < NE) atomicAdd(&deg[ei[e]], 1);
}

// Scan stage 1: per-block (256-elem) sums.
__global__ __launch_bounds__(256) void bsum_kernel(
    const int* __restrict__ deg, int* __restrict__ bsum)
{
    const int i = blockIdx.x * 256 + threadIdx.x;
    int v = (i < NN) ? deg[i] : 0;
#pragma unroll
    for (int off = 32; off; off >>= 1) v += __shfl_down(v, off, 64);
    __shared__ int ws[4];
    const int lane = threadIdx.x & 63, w = threadIdx.x >> 6;
    if (lane == 0) ws[w] = v;
    __syncthreads();
    if (threadIdx.x == 0) bsum[blockIdx.x] = ws[0] + ws[1] + ws[2] + ws[3];
}

// Scan stage 2: one block scans the 196 partials -> exclusive block offsets.
__global__ __launch_bounds__(256) void bscan_kernel(
    const int* __restrict__ bsum, int* __restrict__ boff)
{
    const int t = threadIdx.x;
    const int v = (t < NB_SCAN) ? bsum[t] : 0;
    const int lane = t & 63, w = t >> 6;
    int s = v;
#pragma unroll
    for (int off = 1; off < 64; off <<= 1) {
        const int u = __shfl_up(s, off, 64);
        if (lane >= off) s += u;
    }
    __shared__ int wsum[4];
    if (lane == 63) wsum[w] = s;
    __syncthreads();
    int add = 0;
    for (int k = 0; k < w; ++k) add += wsum[k];
    if (t < NB_SCAN) boff[t] = add + s - v;   // exclusive
}

// Scan stage 3: local exclusive scan + block offset -> start/cursor.
__global__ __launch_bounds__(256) void sfinal_kernel(
    const int* __restrict__ deg, const int* __restrict__ boff,
    int* __restrict__ start, int* __restrict__ cursor)
{
    const int i = blockIdx.x * 256 + threadIdx.x;
    const int v = (i < NN) ? deg[i] : 0;
    const int lane = threadIdx.x & 63, w = threadIdx.x >> 6;
    int s = v;
#pragma unroll
    for (int off = 1; off < 64; off <<= 1) {
        const int u = __shfl_up(s, off, 64);
        if (lane >= off) s += u;
    }
    __shared__ int wsum[4];
    if (lane == 63) wsum[w] = s;
    __syncthreads();
    int add = boff[blockIdx.x];
    for (int k = 0; k < w; ++k) add += wsum[k];
    if (i < NN) { const int e = add + s - v; start[i] = e; cursor[i] = e; }
    if (blockIdx.x == 0 && threadIdx.x == 0) start[NN] = NE;  // total is static
}

__global__ __launch_bounds__(256) void scatter_pos_kernel(
    const int* __restrict__ ei, int* __restrict__ cursor,
    int* __restrict__ sorted_col)
{
    const int e = blockIdx.x * 256 + threadIdx.x;
    if (e < NE) {
        const int r = ei[e];
        const int p = atomicAdd(&cursor[r], 1);
        sorted_col[p] = ei[NE + e];
    }
}

// ---------------- Aggregate: out[n] = h[n] + sum_{e: row=n} h[col_e] ----
__global__ __launch_bounds__(128) void agg_kernel(
    const int* __restrict__ start, const int* __restrict__ scol,
    const float* __restrict__ h, float* __restrict__ out)
{
    const int n = blockIdx.x;
    const int j = threadIdx.x;
    const int s = start[n];
    const int e = start[n + 1];

    float acc = h[(size_t)n * 128 + j];

    __shared__ int cols[128];
    for (int base = s; base < e; base += 128) {
        const int cnt = min(128, e - base);
        if (j < cnt) cols[j] = scol[base + j];
        __syncthreads();
        int k = 0;
        for (; k + 4 <= cnt; k += 4) {
            const float a0 = h[(size_t)cols[k + 0] * 128 + j];
            const float a1 = h[(size_t)cols[k + 1] * 128 + j];
            const float a2 = h[(size_t)cols[k + 2] * 128 + j];
            const float a3 = h[(size_t)cols[k + 3] * 128 + j];
            acc += a0; acc += a1; acc += a2; acc += a3;
        }
        for (; k < cnt; ++k) acc += h[(size_t)cols[k] * 128 + j];
        __syncthreads();
    }

    out[(size_t)n * 128 + j] = acc;
}

extern "C" void kernel_launch(void* const* d_in, const int* in_sizes, int n_in,
                              void* d_out, int out_size, void* d_ws, size_t ws_size,
                              hipStream_t stream)
{
    const float* x  = (const float*)d_in[0];
    const int*   ei = (const int*)d_in[1];   // int32
    const float* W  = (const float*)d_in[2];
    const float* b  = (const float*)d_in[3];
    float* out = (float*)d_out;

    // Workspace layout
    float* h          = (float*)d_ws;                      // NN*DD floats
    int*   deg        = (int*)(h + (size_t)NN * DD);       // NN
    int*   start      = deg + NN;                          // NN+1
    int*   cursor     = start + NN + 1;                    // NN
    int*   sorted_col = cursor + NN;                       // NE
    int*   bsum       = sorted_col + NE;                   // NB_SCAN
    int*   boff       = bsum + NB_SCAN;                    // NB_SCAN

    zero_deg_kernel<<<NB_SCAN, 256, 0, stream>>>(deg);
    hist_kernel<<<(NE + 255) / 256, 256, 0, stream>>>(ei, deg);
    bsum_kernel<<<NB_SCAN, 256, 0, stream>>>(deg, bsum);
    bscan_kernel<<<1, 256, 0, stream>>>(bsum, boff);
    sfinal_kernel<<<NB_SCAN, 256, 0, stream>>>(deg, boff, start, cursor);
    scatter_pos_kernel<<<(NE + 255) / 256, 256, 0, stream>>>(ei, cursor, sorted_col);

    gemm_mfma<<<(NN + TILE_M - 1) / TILE_M, 256, 0, stream>>>(x, W, b, h);

    agg_kernel<<<NN, 128, 0, stream>>>(start, sorted_col, h, out);
}

// Round 4
// 226.602 us; speedup vs baseline: 6.4610x; 1.0862x over previous
//
#include <hip/hip_runtime.h>

#define NN 50000
#define NE 800000
#define DD 128
#define TILE_M 64
#define WPAD 136          // 128 + 8 bf16 pad -> 2-way-max LDS bank aliasing (free)
#define NB_SCAN ((NN + 255) / 256)   // 196 scan blocks
#define NT4 (NE / 4)                 // 200000 threads for 4-edge ILP kernels

typedef __attribute__((ext_vector_type(8))) short short8;
typedef __attribute__((ext_vector_type(4))) float f32x4;

__device__ __forceinline__ unsigned short f2bf(float f) {
    unsigned int u = __float_as_uint(f);
    u += 0x7fffu + ((u >> 16) & 1u);   // RNE
    return (unsigned short)(u >> 16);
}

// ---------------- GEMM: h = x @ W^T + b  (bf16 MFMA) ----------------
// Writes h (fp32, residual-exact) and hbf (bf16, for the gather stream).
__global__ __launch_bounds__(256) void gemm_mfma(
    const float* __restrict__ x, const float* __restrict__ W,
    const float* __restrict__ b, float* __restrict__ h,
    unsigned short* __restrict__ hbf)
{
    __shared__ unsigned short Wl[128 * WPAD];
    __shared__ unsigned short xl[TILE_M * WPAD];

    const int t = threadIdx.x;

    for (int i = t; i < 128 * 32; i += 256) {
        const int r = i >> 5, c4 = (i & 31) << 2;
        const float4 w4 = *(const float4*)(W + r * 128 + c4);
        unsigned short* dst = &Wl[r * WPAD + c4];
        dst[0] = f2bf(w4.x); dst[1] = f2bf(w4.y);
        dst[2] = f2bf(w4.z); dst[3] = f2bf(w4.w);
    }

    const int row0 = blockIdx.x * TILE_M;
#pragma unroll
    for (int i = 0; i < 8; ++i) {
        const int idx = i * 256 + t;
        const int r = idx >> 5, c4 = (idx & 31) << 2;
        int gr = row0 + r; if (gr > NN - 1) gr = NN - 1;
        const float4 v = *(const float4*)(x + (size_t)gr * 128 + c4);
        unsigned short* dst = &xl[r * WPAD + c4];
        dst[0] = f2bf(v.x); dst[1] = f2bf(v.y);
        dst[2] = f2bf(v.z); dst[3] = f2bf(v.w);
    }

    const int lane = t & 63;
    const int wave = t >> 6;
    const int m16  = lane & 15;
    const int quad = lane >> 4;

    float bias[8];
#pragma unroll
    for (int nt = 0; nt < 8; ++nt) bias[nt] = b[nt * 16 + m16];

    __syncthreads();

    const int am = wave * 16 + m16;
    short8 afrag[4];
#pragma unroll
    for (int kc = 0; kc < 4; ++kc)
        afrag[kc] = *(const short8*)&xl[am * WPAD + kc * 32 + quad * 8];

    f32x4 acc[8];
#pragma unroll
    for (int nt = 0; nt < 8; ++nt) acc[nt] = (f32x4){0.f, 0.f, 0.f, 0.f};

#pragma unroll
    for (int kc = 0; kc < 4; ++kc) {
#pragma unroll
        for (int nt = 0; nt < 8; ++nt) {
            const short8 bfrag =
                *(const short8*)&Wl[(nt * 16 + m16) * WPAD + kc * 32 + quad * 8];
            acc[nt] = __builtin_amdgcn_mfma_f32_16x16x32_bf16(
                afrag[kc], bfrag, acc[nt], 0, 0, 0);
        }
    }

    const int rbase = row0 + wave * 16 + quad * 4;
#pragma unroll
    for (int nt = 0; nt < 8; ++nt) {
#pragma unroll
        for (int r = 0; r < 4; ++r) {
            const int grow = rbase + r;
            if (grow < NN) {
                const float v = acc[nt][r] + bias[nt];
                h[(size_t)grow * 128 + nt * 16 + m16]   = v;
                hbf[(size_t)grow * 128 + nt * 16 + m16] = f2bf(v);
            }
        }
    }
}

// ---------------- CSR construction ----------------
__global__ __launch_bounds__(256) void zero_deg_kernel(int* __restrict__ deg)
{
    const int i = blockIdx.x * 256 + threadIdx.x;
    if (i < NN) deg[i] = 0;
}

// 4 edges/thread, fire-and-forget atomics.
__global__ __launch_bounds__(256) void hist_kernel(
    const int* __restrict__ ei, int* __restrict__ deg)
{
    const int t = blockIdx.x * 256 + threadIdx.x;
    if (t >= NT4) return;
    const int r0 = ei[t];
    const int r1 = ei[t + NT4];
    const int r2 = ei[t + 2 * NT4];
    const int r3 = ei[t + 3 * NT4];
    atomicAdd(&deg[r0], 1);
    atomicAdd(&deg[r1], 1);
    atomicAdd(&deg[r2], 1);
    atomicAdd(&deg[r3], 1);
}

__global__ __launch_bounds__(256) void bsum_kernel(
    const int* __restrict__ deg, int* __restrict__ bsum)
{
    const int i = blockIdx.x * 256 + threadIdx.x;
    int v = (i < NN) ? deg[i] : 0;
#pragma unroll
    for (int off = 32; off; off >>= 1) v += __shfl_down(v, off, 64);
    __shared__ int ws[4];
    const int lane = threadIdx.x & 63, w = threadIdx.x >> 6;
    if (lane == 0) ws[w] = v;
    __syncthreads();
    if (threadIdx.x == 0) bsum[blockIdx.x] = ws[0] + ws[1] + ws[2] + ws[3];
}

__global__ __launch_bounds__(256) void bscan_kernel(
    const int* __restrict__ bsum, int* __restrict__ boff)
{
    const int t = threadIdx.x;
    const int v = (t < NB_SCAN) ? bsum[t] : 0;
    const int lane = t & 63, w = t >> 6;
    int s = v;
#pragma unroll
    for (int off = 1; off < 64; off <<= 1) {
        const int u = __shfl_up(s, off, 64);
        if (lane >= off) s += u;
    }
    __shared__ int wsum[4];
    if (lane == 63) wsum[w] = s;
    __syncthreads();
    int add = 0;
    for (int k = 0; k < w; ++k) add += wsum[k];
    if (t < NB_SCAN) boff[t] = add + s - v;
}

__global__ __launch_bounds__(256) void sfinal_kernel(
    const int* __restrict__ deg, const int* __restrict__ boff,
    int* __restrict__ start, int* __restrict__ cursor)
{
    const int i = blockIdx.x * 256 + threadIdx.x;
    const int v = (i < NN) ? deg[i] : 0;
    const int lane = threadIdx.x & 63, w = threadIdx.x >> 6;
    int s = v;
#pragma unroll
    for (int off = 1; off < 64; off <<= 1) {
        const int u = __shfl_up(s, off, 64);
        if (lane >= off) s += u;
    }
    __shared__ int wsum[4];
    if (lane == 63) wsum[w] = s;
    __syncthreads();
    int add = boff[blockIdx.x];
    for (int k = 0; k < w; ++k) add += wsum[k];
    if (i < NN) { const int e = add + s - v; start[i] = e; cursor[i] = e; }
    if (blockIdx.x == 0 && threadIdx.x == 0) start[NN] = NE;
}

// 4 edges/thread: 4 independent atomic->store chains hide atomic latency.
__global__ __launch_bounds__(256) void scatter_pos_kernel(
    const int* __restrict__ ei, int* __restrict__ cursor,
    int* __restrict__ sorted_col)
{
    const int t = blockIdx.x * 256 + threadIdx.x;
    if (t >= NT4) return;
    const int r0 = ei[t];
    const int r1 = ei[t + NT4];
    const int r2 = ei[t + 2 * NT4];
    const int r3 = ei[t + 3 * NT4];
    const int c0 = ei[NE + t];
    const int c1 = ei[NE + t + NT4];
    const int c2 = ei[NE + t + 2 * NT4];
    const int c3 = ei[NE + t + 3 * NT4];
    const int p0 = atomicAdd(&cursor[r0], 1);
    const int p1 = atomicAdd(&cursor[r1], 1);
    const int p2 = atomicAdd(&cursor[r2], 1);
    const int p3 = atomicAdd(&cursor[r3], 1);
    sorted_col[p0] = c0;
    sorted_col[p1] = c1;
    sorted_col[p2] = c2;
    sorted_col[p3] = c3;
}

// ---------------- Aggregate: out[n] = h[n] + sum h[col_e] ----------------
// One wave per node; lane owns 2 columns (ushort2 bf16 gathers, fp32 acc).
// Col indices loaded 64-at-a-time coalesced, shfl-broadcast; 8 gathers in flight.
__global__ __launch_bounds__(256) void agg_kernel(
    const int* __restrict__ start, const int* __restrict__ scol,
    const float* __restrict__ h, const unsigned short* __restrict__ hbf,
    float* __restrict__ out)
{
    const int n = (blockIdx.x * 256 + threadIdx.x) >> 6;  // node (wave-uniform)
    if (n >= NN) return;
    const int lane = threadIdx.x & 63;

    const int s = start[n];
    const int e = start[n + 1];

    float2 acc = *(const float2*)(h + (size_t)n * 128 + lane * 2);

    for (int base = s; base < e; base += 64) {
        const int m = min(e - base, 64);
        int idx = 0;
        if (lane < m) idx = scol[base + lane];

        int k = 0;
        for (; k + 8 <= m; k += 8) {
            const int c0 = __shfl(idx, k + 0, 64);
            const int c1 = __shfl(idx, k + 1, 64);
            const int c2 = __shfl(idx, k + 2, 64);
            const int c3 = __shfl(idx, k + 3, 64);
            const int c4 = __shfl(idx, k + 4, 64);
            const int c5 = __shfl(idx, k + 5, 64);
            const int c6 = __shfl(idx, k + 6, 64);
            const int c7 = __shfl(idx, k + 7, 64);
            const unsigned int p0 = *(const unsigned int*)(hbf + (size_t)c0 * 128 + lane * 2);
            const unsigned int p1 = *(const unsigned int*)(hbf + (size_t)c1 * 128 + lane * 2);
            const unsigned int p2 = *(const unsigned int*)(hbf + (size_t)c2 * 128 + lane * 2);
            const unsigned int p3 = *(const unsigned int*)(hbf + (size_t)c3 * 128 + lane * 2);
            const unsigned int p4 = *(const unsigned int*)(hbf + (size_t)c4 * 128 + lane * 2);
            const unsigned int p5 = *(const unsigned int*)(hbf + (size_t)c5 * 128 + lane * 2);
            const unsigned int p6 = *(const unsigned int*)(hbf + (size_t)c6 * 128 + lane * 2);
            const unsigned int p7 = *(const unsigned int*)(hbf + (size_t)c7 * 128 + lane * 2);
            acc.x += __uint_as_float(p0 << 16) + __uint_as_float(p1 << 16)
                   + __uint_as_float(p2 << 16) + __uint_as_float(p3 << 16)
                   + __uint_as_float(p4 << 16) + __uint_as_float(p5 << 16)
                   + __uint_as_float(p6 << 16) + __uint_as_float(p7 << 16);
            acc.y += __uint_as_float(p0 & 0xffff0000u) + __uint_as_float(p1 & 0xffff0000u)
                   + __uint_as_float(p2 & 0xffff0000u) + __uint_as_float(p3 & 0xffff0000u)
                   + __uint_as_float(p4 & 0xffff0000u) + __uint_as_float(p5 & 0xffff0000u)
                   + __uint_as_float(p6 & 0xffff0000u) + __uint_as_float(p7 & 0xffff0000u);
        }
        for (; k < m; ++k) {
            const int c = __shfl(idx, k, 64);
            const unsigned int p = *(const unsigned int*)(hbf + (size_t)c * 128 + lane * 2);
            acc.x += __uint_as_float(p << 16);
            acc.y += __uint_as_float(p & 0xffff0000u);
        }
    }

    *(float2*)(out + (size_t)n * 128 + lane * 2) = acc;
}

extern "C" void kernel_launch(void* const* d_in, const int* in_sizes, int n_in,
                              void* d_out, int out_size, void* d_ws, size_t ws_size,
                              hipStream_t stream)
{
    const float* x  = (const float*)d_in[0];
    const int*   ei = (const int*)d_in[1];   // int32
    const float* W  = (const float*)d_in[2];
    const float* b  = (const float*)d_in[3];
    float* out = (float*)d_out;

    // Workspace layout
    float*          h   = (float*)d_ws;                          // NN*DD fp32
    unsigned short* hbf = (unsigned short*)(h + (size_t)NN * DD);// NN*DD bf16
    int* deg        = (int*)(hbf + (size_t)NN * DD);             // NN
    int* start      = deg + NN;                                  // NN+1
    int* cursor     = start + NN + 1;                            // NN
    int* sorted_col = cursor + NN;                               // NE
    int* bsum       = sorted_col + NE;                           // NB_SCAN
    int* boff       = bsum + NB_SCAN;                            // NB_SCAN

    zero_deg_kernel<<<NB_SCAN, 256, 0, stream>>>(deg);
    hist_kernel<<<(NT4 + 255) / 256, 256, 0, stream>>>(ei, deg);
    bsum_kernel<<<NB_SCAN, 256, 0, stream>>>(deg, bsum);
    bscan_kernel<<<1, 256, 0, stream>>>(bsum, boff);
    sfinal_kernel<<<NB_SCAN, 256, 0, stream>>>(deg, boff, start, cursor);
    scatter_pos_kernel<<<(NT4 + 255) / 256, 256, 0, stream>>>(ei, cursor, sorted_col);

    gemm_mfma<<<(NN + TILE_M - 1) / TILE_M, 256, 0, stream>>>(x, W, b, h, hbf);

    agg_kernel<<<(NN * 64 + 255) / 256, 256, 0, stream>>>(start, sorted_col, h, hbf, out);
}